// Round 9
// baseline (175.627 us; speedup 1.0000x reference)
//
#include <hip/hip_runtime.h>

typedef float f4 __attribute__((ext_vector_type(4)));
typedef float f2 __attribute__((ext_vector_type(2)));
typedef float f32x4 __attribute__((ext_vector_type(4)));
typedef short bf16x8 __attribute__((ext_vector_type(8)));
typedef unsigned short u16x8 __attribute__((ext_vector_type(8)));

__device__ inline unsigned short f2bf(float f) {
  unsigned u = __float_as_uint(f);
  return (unsigned short)((u + 0x7FFF + ((u >> 16) & 1)) >> 16);
}

// prep: 3 weight transposes (f32 -> bf16, WT[c][k]=W[k][c]) + histogram + packed edges
__global__ __launch_bounds__(256) void prep(
    const float* __restrict__ Ws, const float* __restrict__ Wr,
    const float* __restrict__ Wh, const int* __restrict__ edges, int n_edge,
    unsigned short* __restrict__ WsT, unsigned short* __restrict__ WrT,
    unsigned short* __restrict__ WhT, int* __restrict__ counts,
    uint2* __restrict__ epk) {
  const int t = threadIdx.x;
  int b = blockIdx.x;
  if (b < 192) {
    int wsel = b >> 6;
    const float* W = wsel == 0 ? Ws : (wsel == 1 ? Wr : Wh);
    unsigned short* WT = wsel == 0 ? WsT : (wsel == 1 ? WrT : WhT);
    int e = (b & 63) * 256 + t;  // 0..16383
    int cc = e >> 7, kk = e & 127;
    WT[e] = f2bf(W[kk * 128 + cc]);
    return;
  }
  b -= 192;
  int e = b * 256 + t;
  if (e < n_edge) {
    int rel = edges[(size_t)e * 6 + 2];
    int2 so = *(const int2*)(edges + (size_t)e * 6 + 4);  // sub, obj
    atomicAdd(&counts[so.y], 1);
    epk[e] = make_uint2((unsigned)so.x | ((unsigned)rel << 17), (unsigned)so.y);
  }
}

// Dual-output GEMM per 64-row f32 tile:
//   attn = src@Wx -> fp8 at rec+row*384+256 (128B);  msg = src@Wh -> bf16 at rec+row*384 (256B)
__global__ __launch_bounds__(256) void gemm_dual(
    const float* __restrict__ hidden, int M, int nbN,
    const float* __restrict__ rela, int relv,
    const unsigned short* __restrict__ WsT, const unsigned short* __restrict__ WrT,
    const unsigned short* __restrict__ WhT,
    char* __restrict__ rec, char* __restrict__ relrec) {
  __shared__ __align__(16) char lds[81920];  // A 16K | Wx 32K | Wh 32K
  const int t = threadIdx.x;
  int b = blockIdx.x;
  const float* src;
  const unsigned short* WxT;
  char* out;
  int rows, row0;
  if (b < nbN) { src = hidden; WxT = WsT; out = rec; rows = M; row0 = b * 64; }
  else { src = rela; WxT = WrT; out = relrec; rows = relv; row0 = (b - nbN) * 64; }

#pragma unroll
  for (int i = 0; i < 8; ++i) {
    int m = i * 256 + t;
    int sw = (m * 16) ^ (((m >> 4) & 7) << 4);
    *(u16x8*)(lds + 16384 + sw) = ((const u16x8*)WxT)[m];
    *(u16x8*)(lds + 49152 + sw) = ((const u16x8*)WhT)[m];
  }
#pragma unroll
  for (int i = 0; i < 4; ++i) {
    int m = i * 256 + t;
    int r = m >> 4, c = m & 15;
    int gr = row0 + r;
    if (gr > rows - 1) gr = rows - 1;
    const float* s = src + (size_t)gr * 128 + c * 8;
    f4 lo = *(const f4*)s, hi = *(const f4*)(s + 4);
    u16x8 v;
    v[0] = f2bf(lo.x); v[1] = f2bf(lo.y); v[2] = f2bf(lo.z); v[3] = f2bf(lo.w);
    v[4] = f2bf(hi.x); v[5] = f2bf(hi.y); v[6] = f2bf(hi.z); v[7] = f2bf(hi.w);
    *(u16x8*)(lds + ((m * 16) ^ ((r & 7) << 4))) = v;
  }
  __syncthreads();

  const int w = t >> 6, l = t & 63, lr = l & 15, lg = l >> 4;
  const int rowA = w * 16 + lr;
  bf16x8 afr[4];
#pragma unroll
  for (int k0 = 0; k0 < 4; ++k0)
    afr[k0] = *(const bf16x8*)(lds + rowA * 256 + ((k0 * 64 + lg * 16) ^ ((rowA & 7) << 4)));

  {
    f32x4 acc[8] = {};
#pragma unroll
    for (int k0 = 0; k0 < 4; ++k0) {
      int kb = k0 * 64 + lg * 16;
#pragma unroll
      for (int c0 = 0; c0 < 8; ++c0) {
        int cr = c0 * 16 + lr;
        bf16x8 bfr = *(const bf16x8*)(lds + 16384 + cr * 256 + (kb ^ ((cr & 7) << 4)));
        acc[c0] = __builtin_amdgcn_mfma_f32_16x16x32_bf16(afr[k0], bfr, acc[c0], 0, 0, 0);
      }
    }
#pragma unroll
    for (int c0 = 0; c0 < 8; ++c0) {
      int col = c0 * 16 + lr;
#pragma unroll
      for (int j = 0; j < 4; ++j) {
        int grow = row0 + w * 16 + lg * 4 + j;
        if (grow < rows) {
          unsigned pk = __builtin_amdgcn_cvt_pk_fp8_f32(acc[c0][j], acc[c0][j], 0, false);
          *(unsigned char*)(out + (size_t)grow * 384 + 256 + col) = (unsigned char)pk;
        }
      }
    }
  }
  {
    f32x4 acc[8] = {};
#pragma unroll
    for (int k0 = 0; k0 < 4; ++k0) {
      int kb = k0 * 64 + lg * 16;
#pragma unroll
      for (int c0 = 0; c0 < 8; ++c0) {
        int cr = c0 * 16 + lr;
        bf16x8 bfr = *(const bf16x8*)(lds + 49152 + cr * 256 + (kb ^ ((cr & 7) << 4)));
        acc[c0] = __builtin_amdgcn_mfma_f32_16x16x32_bf16(afr[k0], bfr, acc[c0], 0, 0, 0);
      }
    }
#pragma unroll
    for (int c0 = 0; c0 < 8; ++c0) {
      int col = c0 * 16 + lr;
#pragma unroll
      for (int j = 0; j < 4; ++j) {
        int grow = row0 + w * 16 + lg * 4 + j;
        if (grow < rows)
          *(unsigned short*)(out + (size_t)grow * 384 + col * 2) = f2bf(acc[c0][j]);
      }
    }
  }
}

// Single-pass exclusive scan, decoupled lookback.
__global__ __launch_bounds__(256) void scan_lookback(
    const int* __restrict__ counts, int M, int n_edge, int* __restrict__ status,
    int* __restrict__ offsets, int* __restrict__ cursor) {
  const int t = threadIdx.x, b = blockIdx.x;
  const int idx = b * 256 + t;
  int c = (idx < M) ? counts[idx] : 0;
  const int lane = t & 63, w = t >> 6;
  int s = c;
  for (int off = 1; off < 64; off <<= 1) {
    int o = __shfl_up(s, off, 64);
    if (lane >= off) s += o;
  }
  __shared__ int wsum[4], wpre[4];
  __shared__ int blk_prefix;
  if (lane == 63) wsum[w] = s;
  __syncthreads();
  if (t == 0) {
    int r = 0;
#pragma unroll
    for (int i = 0; i < 4; ++i) { wpre[i] = r; r += wsum[i]; }
    unsigned pub = ((b == 0 ? 2u : 1u) << 30) | (unsigned)r;
    __hip_atomic_store(&status[b], (int)pub, __ATOMIC_RELEASE, __HIP_MEMORY_SCOPE_AGENT);
    if (b == 0) blk_prefix = 0;
  }
  __syncthreads();
  if (b > 0 && w == 0) {
    int prefix = 0;
    int k = b - 1;
    for (;;) {
      int j = k - lane;
      unsigned v;
      if (j >= 0) {
        do {
          v = (unsigned)__hip_atomic_load(&status[j], __ATOMIC_ACQUIRE,
                                          __HIP_MEMORY_SCOPE_AGENT);
        } while ((v >> 30) == 0u);
      } else {
        v = 2u << 30;
      }
      int val = (int)(v & 0x3FFFFFFFu);
      unsigned long long incl = __ballot((v >> 30) == 2u);
      int l = (int)__ffsll(incl) - 1;
      int contrib = (l >= 0) ? ((lane <= l) ? val : 0) : val;
#pragma unroll
      for (int off = 32; off; off >>= 1) contrib += __shfl_xor(contrib, off, 64);
      prefix += contrib;
      if (l >= 0) break;
      k -= 64;
    }
    if (lane == 0) {
      blk_prefix = prefix;
      int total = wpre[3] + wsum[3];
      __hip_atomic_store(&status[b], (int)((2u << 30) | (unsigned)(prefix + total)),
                         __ATOMIC_RELEASE, __HIP_MEMORY_SCOPE_AGENT);
    }
  }
  __syncthreads();
  int excl = blk_prefix + wpre[w] + s - c;
  if (idx < M) { offsets[idx] = excl; cursor[idx] = excl; }
  if (idx == 0) offsets[M] = n_edge;
}

// CSR scatter from packed edges; emits pre-scaled byte offsets.
__global__ __launch_bounds__(256) void scatter_kernel(const uint2* __restrict__ epk,
                                                      int n_edge, int* __restrict__ cursor,
                                                      uint2* __restrict__ esr2) {
  int e = blockIdx.x * 256 + threadIdx.x;
  if (e < n_edge) {
    uint2 pe = epk[e];
    int pos = atomicAdd(&cursor[pe.y], 1);
    unsigned sub = pe.x & 0x1FFFF, rel = pe.x >> 17;
    esr2[pos] = make_uint2(sub * 384u, rel * 384u);
  }
}

template <bool HI>
__device__ inline f2 pk8(unsigned u) {
  return __builtin_amdgcn_cvt_pk_f32_fp8(u, HI);
}

// Wave = 1 node. 4x16-lane groups, each owns a CONTIGUOUS quarter of the edge
// list, unrolled x4 (16 edge gather-sets in flight per wave). f2-packed math.
__global__ __launch_bounds__(256) void node_agg(
    const int* __restrict__ offsets, const uint2* __restrict__ esr2,
    const char* __restrict__ rec, const char* __restrict__ relrec,
    float* __restrict__ out,
    const float* __restrict__ w_alpha, const float* __restrict__ w_b, int M) {
  const int lane = threadIdx.x & 63;
  const int g = lane >> 4, gl = lane & 15;
  const int n = (int)((blockIdx.x * 256u + threadIdx.x) >> 6);
  if (n >= M) return;
  const unsigned bH = gl * 16u, bA = 256u + gl * 8u;
  const float LOG2E = 1.44269504f;
  f2 wap[4];
#pragma unroll
  for (int k = 0; k < 4; ++k) wap[k] = ((const f2*)w_alpha)[gl * 4 + k] * LOG2E;
  const float bb = w_b[0] * LOG2E;

  const int beg = offsets[n], end = offsets[n + 1];
  const int len = end - beg;
  const int q = len >> 2, rem = len & 3;
  const int gbeg = beg + g * q + min(g, rem);
  const int gend = gbeg + q + (g < rem ? 1 : 0);

  f2 acc2[4] = {};

  for (int j = gbeg; j < gend; j += 4) {
    const int jm = gend - 1;
    uint2 o[4];
#pragma unroll
    for (int s = 0; s < 4; ++s) {
      int jj = j + s;
      o[s] = esr2[jj > jm ? jm : jj];
    }
    u16x8 h[4], r[4];
    uint2 as[4], ar[4];
#pragma unroll
    for (int s = 0; s < 4; ++s) {
      h[s] = *(const u16x8*)(rec + o[s].x + bH);
      as[s] = *(const uint2*)(rec + o[s].x + bA);
      r[s] = *(const u16x8*)(relrec + o[s].y + bH);
      ar[s] = *(const uint2*)(relrec + o[s].y + bA);
    }
    float al[4];
#pragma unroll
    for (int s = 0; s < 4; ++s) {
      f2 s0 = pk8<false>(as[s].x) + pk8<false>(ar[s].x);
      f2 s1 = pk8<true>(as[s].x) + pk8<true>(ar[s].x);
      f2 s2 = pk8<false>(as[s].y) + pk8<false>(ar[s].y);
      f2 s3 = pk8<true>(as[s].y) + pk8<true>(ar[s].y);
      s0.x = fmaxf(s0.x, 0.f); s0.y = fmaxf(s0.y, 0.f);
      s1.x = fmaxf(s1.x, 0.f); s1.y = fmaxf(s1.y, 0.f);
      s2.x = fmaxf(s2.x, 0.f); s2.y = fmaxf(s2.y, 0.f);
      s3.x = fmaxf(s3.x, 0.f); s3.y = fmaxf(s3.y, 0.f);
      f2 pp = s0 * wap[0];
      pp += s1 * wap[1];
      pp += s2 * wap[2];
      pp += s3 * wap[3];
      float p = pp.x + pp.y;
#pragma unroll
      for (int off = 1; off <= 8; off <<= 1) p += __shfl_xor(p, off, 64);
      float a = __builtin_amdgcn_rcpf(1.f + __builtin_amdgcn_exp2f(-(p + bb)));
      al[s] = (j + s <= jm) ? a : 0.f;
    }
#pragma unroll
    for (int s = 0; s < 4; ++s) {
      const uint4 hu = *(const uint4*)&h[s];
      const uint4 ru = *(const uint4*)&r[s];
      const unsigned hd[4] = {hu.x, hu.y, hu.z, hu.w};
      const unsigned rd[4] = {ru.x, ru.y, ru.z, ru.w};
#pragma unroll
      for (int k = 0; k < 4; ++k) {
        f2 m;
        m.x = __uint_as_float(hd[k] << 16) + __uint_as_float(rd[k] << 16);
        m.y = __uint_as_float(hd[k] & 0xFFFF0000u) + __uint_as_float(rd[k] & 0xFFFF0000u);
        acc2[k] += al[s] * m;
      }
    }
  }

#pragma unroll
  for (int k = 0; k < 4; ++k) {
    acc2[k].x += __shfl_xor(acc2[k].x, 16, 64);
    acc2[k].y += __shfl_xor(acc2[k].y, 16, 64);
    acc2[k].x += __shfl_xor(acc2[k].x, 32, 64);
    acc2[k].y += __shfl_xor(acc2[k].y, 32, 64);
  }
  if (g == 0) {
    f4 lo = {acc2[0].x, acc2[0].y, acc2[1].x, acc2[1].y};
    f4 hi = {acc2[2].x, acc2[2].y, acc2[3].x, acc2[3].y};
    float* dst = out + (size_t)n * 128 + gl * 8;
    *(f4*)dst = lo;
    *(f4*)(dst + 4) = hi;
  }
}

extern "C" void kernel_launch(void* const* d_in, const int* in_sizes, int n_in,
                              void* d_out, int out_size, void* d_ws, size_t ws_size,
                              hipStream_t stream) {
  const float* hidden = (const float*)d_in[0];
  const int* edges = (const int*)d_in[1];
  const float* rela = (const float*)d_in[4];
  const float* Ws = (const float*)d_in[5];
  const float* Wr = (const float*)d_in[6];
  const float* wa = (const float*)d_in[7];
  const float* wb = (const float*)d_in[8];
  const float* Wh = (const float*)d_in[9];

  const int M = in_sizes[0] / 128;     // 50000
  const int n_edge = in_sizes[1] / 6;  // 640000
  const int relv = in_sizes[4] / 128;  // 1003
  const int NB = (M + 255) / 256;
  const int BE = (n_edge + 255) / 256;

  char* ws = (char*)d_ws;
  size_t off = 0;
  char* rec = ws; off += ((size_t)M * 384 + 255) & ~255ull;
  char* relrec = ws + off; off += ((size_t)relv * 384 + 255) & ~255ull;
  unsigned short* WsT = (unsigned short*)(ws + off); off += 32768;
  unsigned short* WrT = (unsigned short*)(ws + off); off += 32768;
  unsigned short* WhT = (unsigned short*)(ws + off); off += 32768;
  uint2* esr2 = (uint2*)(ws + off); off += (size_t)n_edge * 8;
  uint2* epk = (uint2*)(ws + off); off += (size_t)n_edge * 8;
  int* counts = (int*)(ws + off); off += (size_t)M * 4;
  int* status = (int*)(ws + off); off += 4096;
  int* offsets = (int*)(ws + off); off += ((size_t)(M + 1) * 4 + 255) & ~255ull;
  int* cursor = (int*)(ws + off);
  float* out = (float*)d_out;

  (void)hipMemsetAsync(counts, 0, (size_t)M * 4 + 4096, stream);

  prep<<<192 + BE, 256, 0, stream>>>(Ws, Wr, Wh, edges, n_edge, WsT, WrT, WhT,
                                     counts, epk);

  const int nbN = (M + 63) / 64;
  gemm_dual<<<nbN + (relv + 63) / 64, 256, 0, stream>>>(hidden, M, nbN, rela, relv,
                                                        WsT, WrT, WhT, rec, relrec);

  scan_lookback<<<NB, 256, 0, stream>>>(counts, M, n_edge, status, offsets, cursor);
  scatter_kernel<<<BE, 256, 0, stream>>>(epk, n_edge, cursor, esr2);

  node_agg<<<(M * 64 + 255) / 256, 256, 0, stream>>>(offsets, esr2, rec, relrec,
                                                     out, wa, wb, M);
}